// Round 10
// baseline (94.471 us; speedup 1.0000x reference)
//
#include <hip/hip_runtime.h>
#include <hip/hip_bf16.h>
#include <stdint.h>

// DIAGNOSTIC ROUND: exact round-5 structure (best so far, 39.2us), replicated 3x
// via gridDim.y so the dispatch exceeds the harness fill dispatches (~75us) and
// surfaces in the top-5 rocprof table with full counters. Replicas 1,2 write
// identical results to d_ws (deterministic, race-free); replica 0 writes d_out.
//
// out[b][co][y][x0] = sum_{ci,ky,kx} x[b][ci][(y+ky-3)%256][(x0+kx-3)%256] * d[b][co][ci][ky][kx]
// Per (b,y-tile) GEMM: tmp[u][n=co*8+kx] = sum_{ci,ky} X[ci][(y+ky-3)%256][u] * w[co][ci][ky][kx]
// epilogue: out[x0] = sum_kx tmp[(x0+kx-3)&255][co*8+kx].  MFMA 32x32x16 bf16 (verified r3-r5).

constexpr int NB = 8, CIN = 64, HH = 256, WW = 256, CO = 3, KK = 7;
constexpr int R = 8;             // output rows per block
constexpr int XROWS = 14;        // staged rows r=0..13 (input y0-3 .. y0+10)
constexpr int CI_CHUNK = 8;
constexpr int NCH = CIN / CI_CHUNK;
constexpr int XBUF = XROWS * 256 * 8;    // u16 elements per X buffer (28672)
constexpr size_t OUTSZ = (size_t)NB * CO * HH * WW;

typedef short bf16x8 __attribute__((ext_vector_type(8)));
typedef float f32x16 __attribute__((ext_vector_type(16)));

__device__ inline uint16_t f2bf(float f) {
    union { __hip_bfloat16 h; uint16_t u; } cv;
    cv.h = __float2bfloat16(f);
    return cv.u;
}

// LDS: Xl[2][14][256][8] bf16 = 114688 B | Bl[32][64][8] bf16 = 32768 B  (147456 total)
// epilogue tmp f32[2][256][33] = 67584 B aliases Xl.
__global__ __launch_bounds__(1024, 4)
void conv_mfma_v3r(const float* __restrict__ x, const float* __restrict__ d,
                   float* __restrict__ outp, float* __restrict__ wsp) {
    __shared__ char smem[2 * XBUF * 2 + 32 * 64 * 8 * 2];
    uint16_t* Xl  = (uint16_t*)smem;
    uint16_t* Bl  = (uint16_t*)(smem + 2 * XBUF * 2);
    float*    tmp = (float*)smem;                      // [2][256][33]

    const int tid  = threadIdx.x;
    const int lane = tid & 63, wv = tid >> 6;          // 16 waves
    const int y_t  = wv >> 1, xh = wv & 1;
    const int l31  = lane & 31, lh = lane >> 5;

    const int rep = blockIdx.y;                        // 0,1,2 identical work
    float* outDst = (rep == 0) ? outp : (wsp + (size_t)(rep - 1) * OUTSZ);

    // XCD swizzle: XCD (blk%8) owns image b; its 32 blocks cover adjacent y-tiles.
    const int blk = blockIdx.x;
    const int b   = blk & 7;
    const int y0  = (blk >> 3) * R;

    const float* xb = x + (size_t)b * CIN * HH * WW;
    const float* db = d + (size_t)b * CO * CIN * KK * KK;

    f32x16 acc[4];
    #pragma unroll
    for (int m = 0; m < 4; ++m)
        #pragma unroll
        for (int i = 0; i < 16; ++i) acc[m][i] = 0.f;

    // ---- stage chunk c of X into buffer `buf` (aligned float4 loads, bf16 pack) ----
    auto stageX = [&](int c, int buf) {
        if (tid < XROWS * 64) {                        // 896 active threads
            const int r = tid >> 6, q = tid & 63;
            const int row = (y0 + r - 3) & (HH - 1);
            const float* p = xb + ((size_t)(c * CI_CHUNK) * HH + row) * WW + q * 4;
            float4 v[8];
            #pragma unroll
            for (int j = 0; j < 8; ++j)
                v[j] = *reinterpret_cast<const float4*>(p + (size_t)j * HH * WW);
            uint16_t* dst = Xl + (size_t)buf * XBUF + (size_t)r * 256 * 8;
            #pragma unroll
            for (int t = 0; t < 4; ++t) {
                uint4 pk;
                pk.x = (uint32_t)f2bf(((const float*)&v[0])[t]) | ((uint32_t)f2bf(((const float*)&v[1])[t]) << 16);
                pk.y = (uint32_t)f2bf(((const float*)&v[2])[t]) | ((uint32_t)f2bf(((const float*)&v[3])[t]) << 16);
                pk.z = (uint32_t)f2bf(((const float*)&v[4])[t]) | ((uint32_t)f2bf(((const float*)&v[5])[t]) << 16);
                pk.w = (uint32_t)f2bf(((const float*)&v[6])[t]) | ((uint32_t)f2bf(((const float*)&v[7])[t]) << 16);
                const int xp = q * 4 + t;
                const int xs = xp ^ ((xp >> 2) & 3);   // bank swizzle (involution)
                *reinterpret_cast<uint4*>(dst + (size_t)xs * 8) = pk;
            }
        }
    };

    // ---- compute chunk c from buffer `buf` ----
    auto compute = [&](int c, int buf) {
        const uint16_t* Xb = Xl + (size_t)buf * XBUF;
        #pragma unroll
        for (int ks = 0; ks < 4; ++ks) {
            const int ky = ks * 2 + lh;
            int r = y_t + ky;                          // <= 14
            if (r >= XROWS) r = 0;                     // only y_t=7,ky=7 (zero weight)
            const int fi = c * 4 + ks;
            const bf16x8 bfrag = *reinterpret_cast<const bf16x8*>(&Bl[(size_t)(fi * 64 + lane) * 8]);
            #pragma unroll
            for (int m = 0; m < 4; ++m) {
                const int xr = xh * 128 + m * 32 + l31;
                const int xs = xr ^ ((xr >> 2) & 3);
                const bf16x8 afrag = *reinterpret_cast<const bf16x8*>(&Xb[((size_t)r * 256 + xs) * 8]);
                acc[m] = __builtin_amdgcn_mfma_f32_32x32x16_bf16(afrag, bfrag, acc[m], 0, 0, 0);
            }
        }
    };

    // ---- prologue: X chunk 0 + ALL of B (32 frags, fragment order) ----
    stageX(0, 0);
    #pragma unroll
    for (int q2 = 0; q2 < 2; ++q2) {
        const int s = tid + q2 * 1024;                 // 2048 slots
        const int fi = s >> 6, ln = s & 63;
        const int cc8 = fi >> 2, ks = fi & 3;
        const int h = ln >> 5, n = ln & 31;
        const int ky = ks * 2 + h, co = n >> 3, kx = n & 7;
        uint16_t vals[8];
        #pragma unroll
        for (int j = 0; j < 8; ++j) {
            float v = 0.f;
            if (co < CO && kx < KK && ky < KK)
                v = db[((size_t)co * CIN + cc8 * 8 + j) * (KK * KK) + ky * KK + kx];
            vals[j] = f2bf(v);
        }
        uint4 pk;
        pk.x = (uint32_t)vals[0] | ((uint32_t)vals[1] << 16);
        pk.y = (uint32_t)vals[2] | ((uint32_t)vals[3] << 16);
        pk.z = (uint32_t)vals[4] | ((uint32_t)vals[5] << 16);
        pk.w = (uint32_t)vals[6] | ((uint32_t)vals[7] << 16);
        *reinterpret_cast<uint4*>(&Bl[(size_t)(fi * 64 + ln) * 8]) = pk;
    }

    // ---- main loop: one barrier per chunk; stage(c+1) overlaps compute(c) ----
    for (int c = 0; c < NCH; ++c) {
        __syncthreads();                               // buf[c&1] writes visible
        if (c + 1 < NCH) stageX(c + 1, (c + 1) & 1);   // writes opposite buffer
        compute(c, c & 1);
    }

    // ---- epilogue: 4 rounds x 2 rows; tmp[2][256][33] aliases Xl ----
    for (int p = 0; p < 4; ++p) {
        __syncthreads();
        if ((y_t >> 1) == p) {
            const int rr = y_t & 1;
            #pragma unroll
            for (int m = 0; m < 4; ++m)
                #pragma unroll
                for (int reg = 0; reg < 16; ++reg) {
                    const int rowloc = (reg & 3) + 8 * (reg >> 2) + 4 * lh;
                    const int u = xh * 128 + m * 32 + rowloc;
                    tmp[((size_t)rr * 256 + u) * 33 + l31] = acc[m][reg];
                }
        }
        __syncthreads();
        #pragma unroll
        for (int it0 = 0; it0 < 2; ++it0) {
            const int it = tid + it0 * 1024;
            if (it < 2 * CO * 256) {                   // 1536 items
                const int rr  = it >= CO * 256;
                const int rem = it - rr * CO * 256;
                const int co  = rem >> 8, x0 = rem & 255;
                float s = 0.f;
                #pragma unroll
                for (int kx = 0; kx < 7; ++kx)
                    s += tmp[((size_t)rr * 256 + ((x0 + kx - 3) & 255)) * 33 + co * 8 + kx];
                outDst[(((size_t)b * CO + co) * HH + (y0 + p * 2 + rr)) * WW + x0] = s;
            }
        }
    }
}

extern "C" void kernel_launch(void* const* d_in, const int* in_sizes, int n_in,
                              void* d_out, int out_size, void* d_ws, size_t ws_size,
                              hipStream_t stream) {
    const float* x = (const float*)d_in[0];
    const float* d = (const float*)d_in[1];
    float* outp = (float*)d_out;
    float* ws   = (float*)d_ws;          // needs 2*OUTSZ*4 = 12.6 MB
    conv_mfma_v3r<<<dim3(NB * (HH / R), 3), 1024, 0, stream>>>(x, d, outp, ws);
}

// Round 12
// 40.169 us; speedup vs baseline: 2.3518x; 2.3518x over previous
//
#include <hip/hip_runtime.h>
#include <hip/hip_bf16.h>
#include <stdint.h>

// out[b][co][y][x0] = sum_{ci,ky,kx} x[b][ci][(y+ky-3)%256][(x0+kx-3)%256] * d[b][co][ci][ky][kx]
// Per (b,y-tile) GEMM: tmp[u][n=co*8+kx] = sum_{ci,ky} X[ci][(y+ky-3)%256][u] * w[co][ci][ky][kx]
// epilogue: out[x0] = sum_kx tmp[(x0+kx-3)&255][co*8+kx].  MFMA 32x32x16 bf16 (C/D + A/B verified r3-r6).
// v8: r5-PROVEN phase structure (unified stage->compute, 1 barrier/chunk, stage regs not
// held across compute) at 512-thr blocks, 2 blocks/CU (72KB LDS) -> two independent
// barrier domains per CU (r10 diagnosed lockstep/latency-bound, not demand-bound).
// Swizzle u^=(u>>4)&15: involution; ds_write_b64 staging = 4B/bank/cy (minimum),
// ds_read_b64 frags = 2 lanes/bank (free). B k-slot mapping = r6-validated CIC=4 scheme.

constexpr int NB = 8, CIN = 64, HH = 256, WW = 256, CO = 3, KK = 7;
constexpr int R = 4;               // output rows per block
constexpr int XROWS = 10;          // staged rows (input y0-3 .. y0+6)
constexpr int CIC = 4;             // ci per chunk
constexpr int NCH = CIN / CIC;     // 16
constexpr int XUNITS = XROWS * 256;          // 8B units per buffer (2560)
constexpr int XBYTES = XUNITS * 8;           // 20480 per buffer
constexpr int BOFF   = 2 * XBYTES;           // 40960
constexpr int SMEMSZ = BOFF + 32 * 64 * 16;  // + 32KB B = 73728

typedef short bf16x4 __attribute__((ext_vector_type(4)));
typedef short bf16x8 __attribute__((ext_vector_type(8)));
typedef float f32x16 __attribute__((ext_vector_type(16)));

__device__ inline uint16_t f2bf(float f) {
    union { __hip_bfloat16 h; uint16_t u; } cv;
    cv.h = __float2bfloat16(f);
    return cv.u;
}
// involution on 0..255: bits0-3 ^= bits4-7. Write (stride-4 units) and read
// (contiguous units) both land at the structural bank minimum (see analysis).
__device__ inline int uswz(int u) { return u ^ ((u >> 4) & 15); }

__global__ __launch_bounds__(512, 4)
void conv_mfma_v8(const float* __restrict__ x, const float* __restrict__ d,
                  float* __restrict__ outp) {
    __shared__ char smem[SMEMSZ];
    float* tmp = (float*)smem;                       // epilogue alias [2][256][33]

    const int tid  = threadIdx.x;
    const int lane = tid & 63, wv = tid >> 6;        // 8 waves
    const int y_t  = wv >> 1, xh = wv & 1;           // wave: row y0+y_t, x-half
    const int l31  = lane & 31, lh = lane >> 5;

    // XCD-pinned: image b = blk%8; 64 adjacent y-tiles per XCD -> halos share L2.
    const int blk = blockIdx.x;
    const int b   = blk & 7;
    const int y0  = (blk >> 3) * R;

    const float* xb = x + (size_t)b * CIN * HH * WW;
    const float* db = d + (size_t)b * CO * CIN * KK * KK;

    f32x16 acc[4];
    #pragma unroll
    for (int m = 0; m < 4; ++m)
        #pragma unroll
        for (int i = 0; i < 16; ++i) acc[m][i] = 0.f;

    // ---- unified stage (r5-proven): load -> convert -> ds_write, inside one phase ----
    auto stageX = [&](int c, int buf) {
        char* dstb = smem + buf * XBYTES;
        for (int it = tid; it < XROWS * 64; it += 512) {   // 640 items
            const int r = it >> 6, q = it & 63;
            const int row = (y0 + r - 3) & (HH - 1);
            const float* p = xb + ((size_t)(c * CIC) * HH + row) * WW + q * 4;
            float4 v0 = *reinterpret_cast<const float4*>(p);
            float4 v1 = *reinterpret_cast<const float4*>(p + (size_t)HH * WW);
            float4 v2 = *reinterpret_cast<const float4*>(p + (size_t)2 * HH * WW);
            float4 v3 = *reinterpret_cast<const float4*>(p + (size_t)3 * HH * WW);
            #pragma unroll
            for (int t = 0; t < 4; ++t) {
                uint2 pk;
                pk.x = (uint32_t)f2bf(((const float*)&v0)[t]) | ((uint32_t)f2bf(((const float*)&v1)[t]) << 16);
                pk.y = (uint32_t)f2bf(((const float*)&v2)[t]) | ((uint32_t)f2bf(((const float*)&v3)[t]) << 16);
                const int us = uswz(q * 4 + t);
                *reinterpret_cast<uint2*>(dstb + (size_t)(r * 256 + us) * 8) = pk;
            }
        }
    };

    // ---- compute chunk c: 2 k-steps (ky quads), 4 m-frags ----
    auto compute = [&](int c, int buf) {
        const char* Xb = smem + buf * XBYTES;
        #pragma unroll
        for (int ks2 = 0; ks2 < 2; ++ks2) {
            const int fi = c * 2 + ks2;
            const bf16x8 bfrag = *reinterpret_cast<const bf16x8*>(
                smem + BOFF + (size_t)(fi * 64 + lane) * 16);
            const int r1 = y_t + ks2 * 4 + lh * 2;   // <= 9, in range
            int r2 = r1 + 1;                         // ==10 only y_t=3,ks2=1,lh=1 (ky=7, zero B)
            if (r2 >= XROWS) r2 = 0;
            #pragma unroll
            for (int m = 0; m < 4; ++m) {
                const int us = uswz(xh * 128 + m * 32 + l31);
                const bf16x4 lo = *reinterpret_cast<const bf16x4*>(Xb + (size_t)(r1 * 256 + us) * 8);
                const bf16x4 hi = *reinterpret_cast<const bf16x4*>(Xb + (size_t)(r2 * 256 + us) * 8);
                bf16x8 a;
                a[0] = lo[0]; a[1] = lo[1]; a[2] = lo[2]; a[3] = lo[3];
                a[4] = hi[0]; a[5] = hi[1]; a[6] = hi[2]; a[7] = hi[3];
                acc[m] = __builtin_amdgcn_mfma_f32_32x32x16_bf16(a, bfrag, acc[m], 0, 0, 0);
            }
        }
    };

    // ---- prologue: X chunk 0 + all 32 B frags (r6-validated CIC=4 k-slot mapping) ----
    stageX(0, 0);
    #pragma unroll
    for (int k = 0; k < 4; ++k) {
        const int s = tid + k * 512;                 // 2048 slots = 32 frags x 64 lanes
        const int fi = s >> 6, ln = s & 63;
        const int c = fi >> 1, ks2 = fi & 1;
        const int n = ln & 31, lh2 = ln >> 5;
        const int co = n >> 3, kx = n & 7;
        uint16_t vals[8];
        #pragma unroll
        for (int j = 0; j < 8; ++j) {
            const int ky = ks2 * 4 + lh2 * 2 + (j >> 2);
            float v = 0.f;
            if (co < CO && kx < KK && ky < KK)
                v = db[((size_t)co * CIN + c * CIC + (j & 3)) * (KK * KK) + ky * KK + kx];
            vals[j] = f2bf(v);
        }
        uint4 pk;
        pk.x = (uint32_t)vals[0] | ((uint32_t)vals[1] << 16);
        pk.y = (uint32_t)vals[2] | ((uint32_t)vals[3] << 16);
        pk.z = (uint32_t)vals[4] | ((uint32_t)vals[5] << 16);
        pk.w = (uint32_t)vals[6] | ((uint32_t)vals[7] << 16);
        *reinterpret_cast<uint4*>(smem + BOFF + (size_t)(fi * 64 + ln) * 16) = pk;
    }

    // ---- main loop (r5-proven): barrier ; stage(c+1) ; compute(c) ----
    for (int c = 0; c < NCH; ++c) {
        __syncthreads();                             // stage(c) writes visible
        if (c + 1 < NCH) stageX(c + 1, (c + 1) & 1); // opposite buffer
        compute(c, c & 1);
    }

    // ---- epilogue: 2 passes x 2 rows; tmp[2][256][33] aliases X+B regions ----
    for (int p = 0; p < 2; ++p) {
        __syncthreads();                             // prior reads (compute/reduce) done
        if ((y_t >> 1) == p) {
            const int rr = y_t & 1;
            #pragma unroll
            for (int m = 0; m < 4; ++m)
                #pragma unroll
                for (int reg = 0; reg < 16; ++reg) {
                    const int rowloc = (reg & 3) + 8 * (reg >> 2) + 4 * lh;
                    const int u = xh * 128 + m * 32 + rowloc;
                    tmp[((size_t)rr * 256 + u) * 33 + l31] = acc[m][reg];
                }
        }
        __syncthreads();
        #pragma unroll
        for (int it0 = 0; it0 < 3; ++it0) {
            const int it = tid + it0 * 512;
            if (it < 2 * CO * 256) {                 // 1536 items
                const int rr  = it / (CO * 256);
                const int rem = it - rr * (CO * 256);
                const int co  = rem >> 8, x0 = rem & 255;
                float s = 0.f;
                #pragma unroll
                for (int kx = 0; kx < 7; ++kx)
                    s += tmp[((size_t)rr * 256 + ((x0 + kx - 3) & 255)) * 33 + co * 8 + kx];
                outp[(((size_t)b * CO + co) * HH + (y0 + p * 2 + rr)) * WW + x0] = s;
            }
        }
    }
}

extern "C" void kernel_launch(void* const* d_in, const int* in_sizes, int n_in,
                              void* d_out, int out_size, void* d_ws, size_t ws_size,
                              hipStream_t stream) {
    const float* x = (const float*)d_in[0];
    const float* d = (const float*)d_in[1];
    float* outp = (float*)d_out;
    conv_mfma_v8<<<dim3(NB * (HH / R)), 512, 0, stream>>>(x, d, outp);
}

// Round 13
// 38.802 us; speedup vs baseline: 2.4347x; 1.0352x over previous
//
#include <hip/hip_runtime.h>
#include <hip/hip_bf16.h>
#include <stdint.h>

// out[b][co][y][x0] = sum_{ci,ky,kx} x[b][ci][(y+ky-3)%256][(x0+kx-3)%256] * d[b][co][ci][ky][kx]
// Per (b,y-tile) GEMM: tmp[u][n=co*8+kx] = sum_{ci,ky} X[ci][(y+ky-3)%256][u] * w[co][ci][ky][kx]
// epilogue: out[x0] = sum_kx tmp[(x0+kx-3)&255][co*8+kx].  MFMA 32x32x16 bf16 (verified r3-r6,r12).
// v9 = r5 byte-for-byte EXCEPT:
//   1. full 4-bit unit swizzle u^=(u>>4)&15 (r12-validated): staging ds_write_b128
//      (stride-4 16B-units) covers all 8 bank groups -> kills the 2.75M SQ_LDS_BANK_CONFLICT
//      measured on r5's 2-bit swizzle in r10. A-frag reads: 2 lanes/addr broadcast = free.
//   2. epilogue 2 passes x 4 rows (tmp[4][256][33]=135KB aliases Xl+Bl=147KB after last
//      compute) instead of 4 passes x 2 rows: -4 barriers, 2x reduce parallelism.

constexpr int NB = 8, CIN = 64, HH = 256, WW = 256, CO = 3, KK = 7;
constexpr int R = 8;             // output rows per block
constexpr int XROWS = 14;        // staged rows r=0..13 (input y0-3 .. y0+10)
constexpr int CI_CHUNK = 8;
constexpr int NCH = CIN / CI_CHUNK;
constexpr int XBUF = XROWS * 256 * 8;    // u16 elements per X buffer (28672)

typedef short bf16x8 __attribute__((ext_vector_type(8)));
typedef float f32x16 __attribute__((ext_vector_type(16)));

__device__ inline uint16_t f2bf(float f) {
    union { __hip_bfloat16 h; uint16_t u; } cv;
    cv.h = __float2bfloat16(f);          // HW RNE convert
    return cv.u;
}
// involution on 0..255 (16B-unit index): bits[3:0] ^= bits[7:4].
// Writers touch units u = 4q+t (stride 4): us%8 = (4(q&3)+t)^((q>>2)&7) covers all
// 8 bank groups -> conflict-free ds_write_b128. Readers: 32 consecutive u, bijective
// within two 16-unit spans, 2 lanes (lh=0/1) per address = broadcast (free).
__device__ inline int uswz(int u) { return u ^ ((u >> 4) & 15); }

// LDS: Xl[2][14][256][8] bf16 = 114688 B | Bl[32][64][8] bf16 = 32768 B  (147456 total)
// epilogue tmp f32[4][256][33] = 135168 B aliases Xl+Bl (after last compute).
__global__ __launch_bounds__(1024, 4)
void conv_mfma_v9(const float* __restrict__ x, const float* __restrict__ d,
                  float* __restrict__ outp) {
    __shared__ char smem[2 * XBUF * 2 + 32 * 64 * 8 * 2];
    uint16_t* Xl  = (uint16_t*)smem;
    uint16_t* Bl  = (uint16_t*)(smem + 2 * XBUF * 2);
    float*    tmp = (float*)smem;                      // [4][256][33]

    const int tid  = threadIdx.x;
    const int lane = tid & 63, wv = tid >> 6;          // 16 waves
    const int y_t  = wv >> 1, xh = wv & 1;
    const int l31  = lane & 31, lh = lane >> 5;

    // XCD swizzle: XCD (blk%8) owns image b; its 32 blocks cover adjacent y-tiles.
    const int blk = blockIdx.x;
    const int b   = blk & 7;
    const int y0  = (blk >> 3) * R;

    const float* xb = x + (size_t)b * CIN * HH * WW;
    const float* db = d + (size_t)b * CO * CIN * KK * KK;

    f32x16 acc[4];
    #pragma unroll
    for (int m = 0; m < 4; ++m)
        #pragma unroll
        for (int i = 0; i < 16; ++i) acc[m][i] = 0.f;

    // ---- stage chunk c of X into buffer `buf` (unified r5-proven phase) ----
    auto stageX = [&](int c, int buf) {
        if (tid < XROWS * 64) {                        // 896 active threads
            const int r = tid >> 6, q = tid & 63;
            const int row = (y0 + r - 3) & (HH - 1);
            const float* p = xb + ((size_t)(c * CI_CHUNK) * HH + row) * WW + q * 4;
            float4 v[8];
            #pragma unroll
            for (int j = 0; j < 8; ++j)
                v[j] = *reinterpret_cast<const float4*>(p + (size_t)j * HH * WW);
            uint16_t* dst = Xl + (size_t)buf * XBUF + (size_t)r * 256 * 8;
            #pragma unroll
            for (int t = 0; t < 4; ++t) {
                uint4 pk;
                pk.x = (uint32_t)f2bf(((const float*)&v[0])[t]) | ((uint32_t)f2bf(((const float*)&v[1])[t]) << 16);
                pk.y = (uint32_t)f2bf(((const float*)&v[2])[t]) | ((uint32_t)f2bf(((const float*)&v[3])[t]) << 16);
                pk.z = (uint32_t)f2bf(((const float*)&v[4])[t]) | ((uint32_t)f2bf(((const float*)&v[5])[t]) << 16);
                pk.w = (uint32_t)f2bf(((const float*)&v[6])[t]) | ((uint32_t)f2bf(((const float*)&v[7])[t]) << 16);
                const int us = uswz(q * 4 + t);        // full 8-group spread
                *reinterpret_cast<uint4*>(dst + (size_t)us * 8) = pk;
            }
        }
    };

    // ---- compute chunk c from buffer `buf` ----
    auto compute = [&](int c, int buf) {
        const uint16_t* Xb = Xl + (size_t)buf * XBUF;
        #pragma unroll
        for (int ks = 0; ks < 4; ++ks) {
            const int ky = ks * 2 + lh;
            int r = y_t + ky;                          // <= 14
            if (r >= XROWS) r = 0;                     // only y_t=7,ky=7 (zero weight)
            const int fi = c * 4 + ks;
            const bf16x8 bfrag = *reinterpret_cast<const bf16x8*>(&Bl[(size_t)(fi * 64 + lane) * 8]);
            #pragma unroll
            for (int m = 0; m < 4; ++m) {
                const int us = uswz(xh * 128 + m * 32 + l31);
                const bf16x8 afrag = *reinterpret_cast<const bf16x8*>(&Xb[((size_t)r * 256 + us) * 8]);
                acc[m] = __builtin_amdgcn_mfma_f32_32x32x16_bf16(afrag, bfrag, acc[m], 0, 0, 0);
            }
        }
    };

    // ---- prologue: X chunk 0 + ALL of B (32 frags, fragment order) ----
    stageX(0, 0);
    #pragma unroll
    for (int q2 = 0; q2 < 2; ++q2) {
        const int s = tid + q2 * 1024;                 // 2048 slots
        const int fi = s >> 6, ln = s & 63;
        const int cc8 = fi >> 2, ks = fi & 3;
        const int h = ln >> 5, n = ln & 31;
        const int ky = ks * 2 + h, co = n >> 3, kx = n & 7;
        uint16_t vals[8];
        #pragma unroll
        for (int j = 0; j < 8; ++j) {
            float v = 0.f;
            if (co < CO && kx < KK && ky < KK)
                v = db[((size_t)co * CIN + cc8 * 8 + j) * (KK * KK) + ky * KK + kx];
            vals[j] = f2bf(v);
        }
        uint4 pk;
        pk.x = (uint32_t)vals[0] | ((uint32_t)vals[1] << 16);
        pk.y = (uint32_t)vals[2] | ((uint32_t)vals[3] << 16);
        pk.z = (uint32_t)vals[4] | ((uint32_t)vals[5] << 16);
        pk.w = (uint32_t)vals[6] | ((uint32_t)vals[7] << 16);
        *reinterpret_cast<uint4*>(&Bl[(size_t)(fi * 64 + ln) * 8]) = pk;
    }

    // ---- main loop (r5-proven): barrier ; stage(c+1) ; compute(c) ----
    for (int c = 0; c < NCH; ++c) {
        __syncthreads();                               // buf[c&1] writes visible
        if (c + 1 < NCH) stageX(c + 1, (c + 1) & 1);   // writes opposite buffer
        compute(c, c & 1);
    }

    // ---- epilogue: 2 passes x 4 rows; tmp[4][256][33] aliases Xl+Bl ----
    for (int p = 0; p < 2; ++p) {
        __syncthreads();                               // prior compute/reduce reads done
        if ((y_t >> 2) == p) {
            const int rr = y_t & 3;
            #pragma unroll
            for (int m = 0; m < 4; ++m)
                #pragma unroll
                for (int reg = 0; reg < 16; ++reg) {
                    const int rowloc = (reg & 3) + 8 * (reg >> 2) + 4 * lh;
                    const int u = xh * 128 + m * 32 + rowloc;
                    tmp[((size_t)rr * 256 + u) * 33 + l31] = acc[m][reg];
                }
        }
        __syncthreads();
        #pragma unroll
        for (int it0 = 0; it0 < 3; ++it0) {
            const int it = tid + it0 * 1024;
            if (it < 4 * CO * 256) {                   // 3072 items
                const int rr  = it / (CO * 256);
                const int rem = it - rr * (CO * 256);
                const int co  = rem >> 8, x0 = rem & 255;
                float s = 0.f;
                #pragma unroll
                for (int kx = 0; kx < 7; ++kx)
                    s += tmp[((size_t)rr * 256 + ((x0 + kx - 3) & 255)) * 33 + co * 8 + kx];
                outp[(((size_t)b * CO + co) * HH + (y0 + p * 4 + rr)) * WW + x0] = s;
            }
        }
    }
}

extern "C" void kernel_launch(void* const* d_in, const int* in_sizes, int n_in,
                              void* d_out, int out_size, void* d_ws, size_t ws_size,
                              hipStream_t stream) {
    const float* x = (const float*)d_in[0];
    const float* d = (const float*)d_in[1];
    float* outp = (float*)d_out;
    conv_mfma_v9<<<dim3(NB * (HH / R)), 1024, 0, stream>>>(x, d, outp);
}